// Round 10
// baseline (2126.929 us; speedup 1.0000x reference)
//
#include <hip/hip_runtime.h>
#include <math.h>

// CTRNN + adaptive DOPRI5 (B=2048, N=1024). Round 10: r6/r7 partition
// (256 blocks x 512 thr; block = 256 rows x 32 cols; rowgroup bid&7 ->
// XCD-local act), with FULLY COALESCED loads everywhere:
//  - A staged per 64-row x 512-half phase; each wave-load = one contiguous
//    1KB half-row (XOR-permuted within the span; LDS linear dest).
//  - W tile cast fp32->fp16 directly into LDS (64KB, swizzled, resident).
//  - 8 waves = 4m x 2n MFMA fragments; thread owns 16 elems, single col.
//  - no-RMW rowbar (6/step) + packed-flag step reduce (1/step, r9-validated).
// State in regs (y/ys fp32, k's fp16 half2 packs). FSAL: stage1 GEMM-free.

typedef float f4 __attribute__((ext_vector_type(4)));
typedef float f32x4 __attribute__((ext_vector_type(4)));
typedef _Float16 half8v __attribute__((ext_vector_type(8)));
typedef _Float16 half2v __attribute__((ext_vector_type(2)));
typedef unsigned long long u64;

#define AS1 __attribute__((address_space(1)))
#define AS3 __attribute__((address_space(3)))

#define NBLK 256
#define NTHR 512

#define E1c (71.0f / 57600.0f)
#define E3c (-71.0f / 16695.0f)
#define E4c (71.0f / 1920.0f)
#define E5c (-17253.0f / 339200.0f)
#define E6c (22.0f / 525.0f)
#define E7c (-1.0f / 40.0f)

#define ALDI(p) __hip_atomic_load((p), __ATOMIC_ACQUIRE, __HIP_MEMORY_SCOPE_AGENT)
#define ASTI(p, v) __hip_atomic_store((p), (v), __ATOMIC_RELEASE, __HIP_MEMORY_SCOPE_AGENT)
#define ALD64(p) __hip_atomic_load((p), __ATOMIC_ACQUIRE, __HIP_MEMORY_SCOPE_AGENT)
#define AST64(p, v) __hip_atomic_store((p), (v), __ATOMIC_RELEASE, __HIP_MEMORY_SCOPE_AGENT)

// ws ints: flg[256*16] @0 (16KB), pk u64[2048] @16KB (16KB) -> 8192 ints.
__global__ void k_zero(int* w) {
  int i = blockIdx.x * blockDim.x + threadIdx.x;
  w[i] = 0;
}

__device__ __forceinline__ float ftanh(float x) {
  x = fminf(fmaxf(x, -9.0f), 9.0f);
  float e = __expf(2.0f * x);
  return (e - 1.0f) / (e + 1.0f);
}

// rowgroup barrier (32 blocks, one flag-line per block, zero RMW)
__device__ __forceinline__ void rowbar(int* flg, int bid, int rg, int e) {
  __syncthreads();
  if (threadIdx.x == 0) { __threadfence(); ASTI(&flg[bid * 16], e); }
  if (threadIdx.x < 32) {
    while (ALDI(&flg[(rg + 8 * (int)threadIdx.x) * 16]) < e)
      __builtin_amdgcn_s_sleep(1);
  }
  __syncthreads();
  __threadfence();
}

// One rc (64-row chunk) of rec = act @ W^T. A: 2 phases of [64 x 512]
// coalesced global_load_lds (1KB contiguous per wave-load, XOR-permuted
// within span). B: LDS-resident swizzled W tile. Wave = (mw=wv>>1, nw=wv&1).
__device__ __forceinline__ f32x4 gemm_rc(const _Float16* __restrict__ act,
                                         const _Float16* Ws, _Float16* As,
                                         int rowBase, int rc,
                                         int l, int wv, int lr, int lk) {
  f32x4 acc = {0.0f, 0.0f, 0.0f, 0.0f};
  const int r7 = lr & 7;
  const _Float16* aRow = As + ((wv >> 1) * 16 + lr) * 512;
  const _Float16* wRow = Ws + ((wv & 1) * 16 + lr) * 1024;
#pragma unroll
  for (int kh = 0; kh < 2; ++kh) {
    __syncthreads();   // prev phase reads done
#pragma unroll
    for (int i = 0; i < 8; ++i) {
      const int rr = wv * 8 + i;
      __builtin_amdgcn_global_load_lds(
          (const AS1 void*)(act + (size_t)(rowBase + rc * 64 + rr) * 1024 +
                            kh * 512 + ((l ^ (rr & 7)) << 3)),
          (AS3 void*)(As + rr * 512 + l * 8), 16, 0, 0);
    }
    __syncthreads();   // staged (drains vmcnt)
#pragma unroll
    for (int kc = 0; kc < 16; ++kc) {
      half8v a = *(const half8v*)(aRow + (((kc * 4 + lk) ^ r7) << 3));
      half8v b = *(const half8v*)(wRow + (((kh * 64 + kc * 4 + lk) ^ r7) << 3));
      acc = __builtin_amdgcn_mfma_f32_16x16x32_f16(a, b, acc, 0, 0, 0);
    }
  }
  return acc;
}

// Stage-S epilogue for one rc; e = rc*4 + q. Thread col fixed.
template <int S>
__device__ __forceinline__ void epi(
    const f32x4 acc, float h, int rc,
    float* y, float* ys, const half2v* dh,
    half2v* k1h, half2v* k2h, half2v* k3h, half2v* k4h, half2v* k5h, half2v* eh,
    float itau, float biasv, _Float16* __restrict__ actOut,
    int rowTh, int col, float* errAcc) {
#pragma unroll
  for (int q = 0; q < 4; ++q) {
    const int e = rc * 4 + q;
    float yv = y[e];
    float ks;
    if constexpr (S == 1) {
      ks = (float)k1h[e >> 1][e & 1];
    } else {
      ks = itau * ((float)dh[e >> 1][e & 1] + acc[q] - ys[e]);
    }
    float nys;
    if constexpr (S == 1) {
      eh[e >> 1][e & 1] = (_Float16)(E1c * ks);
      nys = yv + h * (0.2f * ks);
    } else if constexpr (S == 2) {
      k2h[e >> 1][e & 1] = (_Float16)ks;
      float k1 = (float)k1h[e >> 1][e & 1];
      nys = yv + h * ((3.0f / 40.0f) * k1 + (9.0f / 40.0f) * ks);
    } else if constexpr (S == 3) {
      k3h[e >> 1][e & 1] = (_Float16)ks;
      eh[e >> 1][e & 1] = (_Float16)((float)eh[e >> 1][e & 1] + E3c * ks);
      float k1 = (float)k1h[e >> 1][e & 1], k2 = (float)k2h[e >> 1][e & 1];
      nys = yv + h * ((44.0f / 45.0f) * k1 + (-56.0f / 15.0f) * k2 + (32.0f / 9.0f) * ks);
    } else if constexpr (S == 4) {
      k4h[e >> 1][e & 1] = (_Float16)ks;
      eh[e >> 1][e & 1] = (_Float16)((float)eh[e >> 1][e & 1] + E4c * ks);
      float k1 = (float)k1h[e >> 1][e & 1], k2 = (float)k2h[e >> 1][e & 1];
      float k3 = (float)k3h[e >> 1][e & 1];
      nys = yv + h * ((19372.0f / 6561.0f) * k1 + (-25360.0f / 2187.0f) * k2 +
                      (64448.0f / 6561.0f) * k3 + (-212.0f / 729.0f) * ks);
    } else if constexpr (S == 5) {
      k5h[e >> 1][e & 1] = (_Float16)ks;
      eh[e >> 1][e & 1] = (_Float16)((float)eh[e >> 1][e & 1] + E5c * ks);
      float k1 = (float)k1h[e >> 1][e & 1], k2 = (float)k2h[e >> 1][e & 1];
      float k3 = (float)k3h[e >> 1][e & 1], k4 = (float)k4h[e >> 1][e & 1];
      nys = yv + h * ((9017.0f / 3168.0f) * k1 + (-355.0f / 33.0f) * k2 +
                      (46732.0f / 5247.0f) * k3 + (49.0f / 176.0f) * k4 +
                      (-5103.0f / 18656.0f) * ks);
    } else if constexpr (S == 6) {
      eh[e >> 1][e & 1] = (_Float16)((float)eh[e >> 1][e & 1] + E6c * ks);
      float k1 = (float)k1h[e >> 1][e & 1];
      float k3 = (float)k3h[e >> 1][e & 1], k4 = (float)k4h[e >> 1][e & 1];
      float k5 = (float)k5h[e >> 1][e & 1];
      nys = yv + h * ((35.0f / 384.0f) * k1 + (500.0f / 1113.0f) * k3 +
                      (125.0f / 192.0f) * k4 + (-2187.0f / 6784.0f) * k5 +
                      (11.0f / 84.0f) * ks);
    } else {  // S == 7: k7 -> k2h slot (dead after S5); error norm
      k2h[e >> 1][e & 1] = (_Float16)ks;
      float ev = h * ((float)eh[e >> 1][e & 1] + E7c * ks);
      float sc = 1e-6f + 1e-3f * fmaxf(fabsf(yv), fabsf(ys[e]));
      float r = ev / sc;
      *errAcc += r * r;
      nys = 0.0f;
    }
    if constexpr (S <= 6) {
      ys[e] = nys;
      actOut[(size_t)(rowTh + rc * 64 + q) * 1024 + col] = (_Float16)ftanh(nys + biasv);
    }
  }
}

__global__ __launch_bounds__(NTHR) void k_ode(
    const float* __restrict__ inp, const float* __restrict__ prev,
    const float* __restrict__ tau, const f4* __restrict__ W4,
    const float* __restrict__ iw, const float* __restrict__ bias,
    float* __restrict__ out, int* __restrict__ flg, u64* __restrict__ pk,
    _Float16* __restrict__ ab0, _Float16* __restrict__ ab1) {
  __shared__ _Float16 Ws[32 * 1024];   // 64 KB W tile (kernel-lifetime)
  __shared__ _Float16 As[64 * 512];    // 64 KB A phase buffer
  __shared__ float wsum[8];
  __shared__ float sm[256];
  __shared__ float bc;

  const int tid = (int)threadIdx.x, bid = (int)blockIdx.x;
  const int l = tid & 63, wv = tid >> 6;
  const int lr = l & 15, lk = l >> 4;
  const int rg = bid & 7, cg = bid >> 3;
  const int rowBase = rg * 256, colBase = cg * 32;
  const int col = colBase + (wv & 1) * 16 + lr;
  const int rowTh = rowBase + (wv >> 1) * 16 + lk * 4;   // + rc*64 + q

  // --- W tile: cast fp32 -> fp16 directly into swizzled LDS ---
  {
    const int wr = tid >> 4, tq = tid & 15;   // wr 0..31 (W row = out col)
#pragma unroll
    for (int u = 0; u < 8; ++u) {
      int k0 = tq * 64 + u * 8;
      f4 w0 = W4[(size_t)(colBase + wr) * 256 + (k0 >> 2)];
      f4 w1 = W4[(size_t)(colBase + wr) * 256 + (k0 >> 2) + 1];
      half8v hv;
#pragma unroll
      for (int j = 0; j < 4; ++j) { hv[j] = (_Float16)w0[j]; hv[4 + j] = (_Float16)w1[j]; }
      int slot = (k0 >> 3) ^ (wr & 7);
      *(half8v*)(Ws + wr * 1024 + slot * 8) = hv;
    }
  }

  // --- state init + act1 -> ab1 ---
  float y[16], ysr[16];
  half2v dh[8], k1h[8], k2h[8], k3h[8], k4h[8], k5h[8], eh[8];
  const float itau = 1.0f / tau[col];
  const float biasv = bias[col];
  const float iwv = iw[col];
#pragma unroll
  for (int rc = 0; rc < 4; ++rc)
#pragma unroll
    for (int q = 0; q < 4; ++q) {
      const int e = rc * 4 + q;
      size_t off = (size_t)(rowTh + rc * 64 + q) * 1024 + col;
      float yv = prev[off];
      y[e] = yv;
      ysr[e] = yv;
      dh[e >> 1][e & 1] = (_Float16)(inp[off] * iwv);
      ab1[off] = (_Float16)ftanh(yv + biasv);
    }

  int pe = 1;
  rowbar(flg, bid, rg, pe);   // act1 visible within rowgroup; Ws via barrier

  // initial k1 = itau*(drive + W@act1 - y)
#pragma unroll
  for (int rc = 0; rc < 4; ++rc) {
    f32x4 acc = gemm_rc(ab1, Ws, As, rowBase, rc, l, wv, lr, lk);
#pragma unroll
    for (int q = 0; q < 4; ++q) {
      const int e = rc * 4 + q;
      k1h[e >> 1][e & 1] =
          (_Float16)(itau * ((float)dh[e >> 1][e & 1] + acc[q] - y[e]));
    }
  }

  float t = 0.0f, dtv = 0.1f;
#pragma unroll 1
  for (int s = 0; s < 40; ++s) {
    if (t >= 1.0f - 1e-7f) break;
    const float h = fminf(dtv, 1.0f - t);
    const f32x4 zacc = {0.0f, 0.0f, 0.0f, 0.0f};

    // S1: FSAL, no GEMM; act2 -> ab0
#pragma unroll
    for (int rc = 0; rc < 4; ++rc)
      epi<1>(zacc, h, rc, y, ysr, dh, k1h, k2h, k3h, k4h, k5h, eh,
             itau, biasv, ab0, rowTh, col, nullptr);
    rowbar(flg, bid, rg, ++pe);

#pragma unroll
    for (int rc = 0; rc < 4; ++rc) {
      f32x4 acc = gemm_rc(ab0, Ws, As, rowBase, rc, l, wv, lr, lk);
      epi<2>(acc, h, rc, y, ysr, dh, k1h, k2h, k3h, k4h, k5h, eh,
             itau, biasv, ab1, rowTh, col, nullptr);
    }
    rowbar(flg, bid, rg, ++pe);

#pragma unroll
    for (int rc = 0; rc < 4; ++rc) {
      f32x4 acc = gemm_rc(ab1, Ws, As, rowBase, rc, l, wv, lr, lk);
      epi<3>(acc, h, rc, y, ysr, dh, k1h, k2h, k3h, k4h, k5h, eh,
             itau, biasv, ab0, rowTh, col, nullptr);
    }
    rowbar(flg, bid, rg, ++pe);

#pragma unroll
    for (int rc = 0; rc < 4; ++rc) {
      f32x4 acc = gemm_rc(ab0, Ws, As, rowBase, rc, l, wv, lr, lk);
      epi<4>(acc, h, rc, y, ysr, dh, k1h, k2h, k3h, k4h, k5h, eh,
             itau, biasv, ab1, rowTh, col, nullptr);
    }
    rowbar(flg, bid, rg, ++pe);

#pragma unroll
    for (int rc = 0; rc < 4; ++rc) {
      f32x4 acc = gemm_rc(ab1, Ws, As, rowBase, rc, l, wv, lr, lk);
      epi<5>(acc, h, rc, y, ysr, dh, k1h, k2h, k3h, k4h, k5h, eh,
             itau, biasv, ab0, rowTh, col, nullptr);
    }
    rowbar(flg, bid, rg, ++pe);

#pragma unroll
    for (int rc = 0; rc < 4; ++rc) {
      f32x4 acc = gemm_rc(ab0, Ws, As, rowBase, rc, l, wv, lr, lk);
      epi<6>(acc, h, rc, y, ysr, dh, k1h, k2h, k3h, k4h, k5h, eh,
             itau, biasv, ab1, rowTh, col, nullptr);   // act7 -> ab1
    }
    rowbar(flg, bid, rg, ++pe);

    // S7: GEMM on act7 + error norm (k7 -> k2h slots)
    float errAcc = 0.0f;
#pragma unroll
    for (int rc = 0; rc < 4; ++rc) {
      f32x4 acc = gemm_rc(ab1, Ws, As, rowBase, rc, l, wv, lr, lk);
      epi<7>(acc, h, rc, y, ysr, dh, k1h, k2h, k3h, k4h, k5h, eh,
             itau, biasv, nullptr, rowTh, col, &errAcc);
    }

#pragma unroll
    for (int o = 32; o > 0; o >>= 1) errAcc += __shfl_down(errAcc, o, 64);
    if (l == 0) wsum[wv] = errAcc;
    __syncthreads();
    float sblk = 0.0f;
    if (tid == 0) {
#pragma unroll
      for (int w = 0; w < 8; ++w) sblk += wsum[w];
    }

    // single grid sync + deterministic reduce: packed (epoch|partial), 2 slots
    const u64 epk = (u64)(s + 2);
    const int slot = (int)(epk & 1);
    if (tid == 0)
      AST64(&pk[bid * 8 + slot], (epk << 32) | (u64)__float_as_uint(sblk));
    if (tid < 256) {
      u64 v;
      do {
        v = ALD64(&pk[tid * 8 + slot]);
      } while ((v >> 32) < epk);
      sm[tid] = __uint_as_float((unsigned)v);
    }
    __syncthreads();
    if (tid < 64) {
      float a = sm[tid] + sm[tid + 64] + sm[tid + 128] + sm[tid + 192];
#pragma unroll
      for (int o = 1; o < 64; o <<= 1) a += __shfl_xor(a, o, 64);
      if (tid == 0) bc = a;
    }
    __syncthreads();
    float sd = bc;

    float enorm = fmaxf(sqrtf(sd / 2097152.0f), 1e-10f);
    if (enorm <= 1.0f) {
      t = t + h;
#pragma unroll
      for (int e = 0; e < 16; ++e) y[e] = ysr[e];
#pragma unroll
      for (int i = 0; i < 8; ++i) k1h[i] = k2h[i];   // FSAL: k1 = k7
    }
    float factor = fminf(fmaxf(0.9f * powf(enorm, -0.2f), 0.2f), 5.0f);
    dtv = dtv * factor;
  }

  // --- final output ---
#pragma unroll
  for (int rc = 0; rc < 4; ++rc)
#pragma unroll
    for (int q = 0; q < 4; ++q) {
      const int e = rc * 4 + q;
      out[(size_t)(rowTh + rc * 64 + q) * 1024 + col] = y[e];
    }
}

extern "C" void kernel_launch(void* const* d_in, const int* in_sizes, int n_in,
                              void* d_out, int out_size, void* d_ws, size_t ws_size,
                              hipStream_t stream) {
  const float* inp = (const float*)d_in[0];
  const float* prev = (const float*)d_in[1];
  const float* tau = (const float*)d_in[2];
  const f4* W4 = (const f4*)d_in[3];
  const float* iw = (const float*)d_in[4];
  const float* bias = (const float*)d_in[5];
  float* out = (float*)d_out;

  char* ws = (char*)d_ws;
  const size_t MB = 1024 * 1024;
  int* flg = (int*)ws;                       // 256*16 ints (16 KB)
  u64* pk = (u64*)(ws + 16384);              // 2048 u64 (16 KB)
  _Float16* ab0 = (_Float16*)(ws + 64 * 1024);           // 4 MB
  _Float16* ab1 = (_Float16*)(ws + 64 * 1024 + 4 * MB);  // 4 MB

  k_zero<<<16, 512, 0, stream>>>((int*)ws);
  k_ode<<<NBLK, NTHR, 0, stream>>>(inp, prev, tau, W4, iw, bias, out,
                                   flg, pk, ab0, ab1);
}

// Round 11
// 1133.457 us; speedup vs baseline: 1.8765x; 1.8765x over previous
//
#include <hip/hip_runtime.h>
#include <math.h>

// CTRNN + adaptive DOPRI5 (B=2048, N=1024). Round 11: one launch per step.
// Block = 8 complete batch rows (r9 decomposition: ZERO intra-step
// inter-block communication; act lives in block LDS ping-pong). Kernel
// boundary = the grid sync between steps (r2/r6: dead step ~4us). The
// step's error-norm/controller uses r9's verified single packed-flag
// exchange at step end; block 0 persists Ctl{t,dt}. NEW: W pre-transposed
// to MFMA-fragment-contiguous layout Wf so every wave B-load is one
// contiguous 1KB segment (fixes r9's 85us/GEMM W-gather). FSAL: k1=k7.

typedef float f4 __attribute__((ext_vector_type(4)));
typedef float f32x4 __attribute__((ext_vector_type(4)));
typedef _Float16 half8v __attribute__((ext_vector_type(8)));
typedef _Float16 half4v __attribute__((ext_vector_type(4)));
typedef _Float16 half2v __attribute__((ext_vector_type(2)));
typedef unsigned long long u64;

#define NBLK 256
#define NTHR 512

#define E1c (71.0f / 57600.0f)
#define E3c (-71.0f / 16695.0f)
#define E4c (71.0f / 1920.0f)
#define E5c (-17253.0f / 339200.0f)
#define E6c (22.0f / 525.0f)
#define E7c (-1.0f / 40.0f)

#define ALD64(p) __hip_atomic_load((p), __ATOMIC_ACQUIRE, __HIP_MEMORY_SCOPE_AGENT)
#define AST64(p, v) __hip_atomic_store((p), (v), __ATOMIC_RELEASE, __HIP_MEMORY_SCOPE_AGENT)

struct Ctl { float t, dt; };

__global__ void k_zero(u64* pk) {
  int i = blockIdx.x * blockDim.x + threadIdx.x;
  if (i < 2048) pk[i] = 0ull;
}

__device__ __forceinline__ float ftanh(float x) {
  x = fminf(fmaxf(x, -9.0f), 9.0f);
  float e = __expf(2.0f * x);
  return (e - 1.0f) / (e + 1.0f);
}

// Wf[((ct16*32 + kb)*64 + l)*8 + j] = W[ct16*16 + (l&15)][kb*32 + (l>>4)*8 + j]
__global__ void k_prep(const float* __restrict__ W, _Float16* __restrict__ Wf) {
  int i = blockIdx.x * blockDim.x + threadIdx.x;   // 0..131071
  int l = i & 63, kb = (i >> 6) & 31, ct = i >> 11;
  const float* src = W + (size_t)(ct * 16 + (l & 15)) * 1024 + kb * 32 + (l >> 4) * 8;
  half8v o;
#pragma unroll
  for (int j = 0; j < 8; ++j) o[j] = (_Float16)src[j];
  *(half8v*)(Wf + ((size_t)i << 3)) = o;
}

// y := prev (in d_out); drive := inp*iw (fp16)
__global__ void k_init(const f4* __restrict__ prev, const f4* __restrict__ inp,
                       const f4* __restrict__ iw, f4* __restrict__ y,
                       half4v* __restrict__ dws) {
  int i = blockIdx.x * blockDim.x + threadIdx.x;   // 0..524287 (f4 units)
  f4 p = prev[i];
  y[i] = p;
  f4 v = inp[i];
  f4 w = iw[i & 255];
  half4v d;
#pragma unroll
  for (int j = 0; j < 4; ++j) d[j] = (_Float16)(v[j] * w[j]);
  dws[i] = d;
}

// acc[8] = rec fragments for this wave's 8 col-tiles. A from LDS act
// (row = l&7, XOR-swizzled granules); B from fragment-contiguous Wf
// (one contiguous 1KB segment per wave-load).
__device__ __forceinline__ void gemm8(const char* actB,
                                      const _Float16* __restrict__ wfb,
                                      int l, f32x4 acc[8]) {
#pragma unroll
  for (int ct = 0; ct < 8; ++ct)
#pragma unroll
    for (int q = 0; q < 4; ++q) acc[ct][q] = 0.0f;
  const int r = l & 7, lk = l >> 4;
  const char* arow = actB + r * 2048;
#pragma unroll 2
  for (int kb = 0; kb < 32; ++kb) {
    half8v a = *(const half8v*)(arow + ((((kb << 2) | lk) ^ r) << 4));
#pragma unroll
    for (int ct = 0; ct < 8; ++ct) {
      half8v b = *(const half8v*)(wfb + (((ct << 5) + kb) << 9));
      acc[ct] = __builtin_amdgcn_mfma_f32_16x16x32_f16(a, b, acc[ct], 0, 0, 0);
    }
  }
}

// e = ci*4 + q. Thread owns rows ((l>>4)&1)*4+q, cols wv*128+((l>>5)*4+ci)*16+(l&15).
template <int S>
__device__ __forceinline__ void stage_epi(
    const f32x4 acc[8], float h,
    float* y, float* ys, const half2v* dh,
    half2v* k1h, half2v* k2h, half2v* k3h, half2v* k4h, half2v* k5h, half2v* eh,
    const float* itau4, const float* bias4,
    char* actOut, int wv, int l, float* errAcc) {
  f32x4 sa[4];
  if (l >= 32) { sa[0] = acc[4]; sa[1] = acc[5]; sa[2] = acc[6]; sa[3] = acc[7]; }
  else         { sa[0] = acc[0]; sa[1] = acc[1]; sa[2] = acc[2]; sa[3] = acc[3]; }
#pragma unroll
  for (int ci = 0; ci < 4; ++ci) {
#pragma unroll
    for (int q = 0; q < 4; ++q) {
      const int e = ci * 4 + q;
      float yv = y[e];
      float ks;
      if constexpr (S == 1) {
        ks = (float)k1h[e >> 1][e & 1];
      } else {
        ks = itau4[ci] * ((float)dh[e >> 1][e & 1] + sa[ci][q] - ys[e]);
      }
      float nys;
      if constexpr (S == 1) {
        eh[e >> 1][e & 1] = (_Float16)(E1c * ks);
        nys = yv + h * (0.2f * ks);
      } else if constexpr (S == 2) {
        k2h[e >> 1][e & 1] = (_Float16)ks;
        float k1 = (float)k1h[e >> 1][e & 1];
        nys = yv + h * ((3.0f / 40.0f) * k1 + (9.0f / 40.0f) * ks);
      } else if constexpr (S == 3) {
        k3h[e >> 1][e & 1] = (_Float16)ks;
        eh[e >> 1][e & 1] = (_Float16)((float)eh[e >> 1][e & 1] + E3c * ks);
        float k1 = (float)k1h[e >> 1][e & 1], k2 = (float)k2h[e >> 1][e & 1];
        nys = yv + h * ((44.0f / 45.0f) * k1 + (-56.0f / 15.0f) * k2 + (32.0f / 9.0f) * ks);
      } else if constexpr (S == 4) {
        k4h[e >> 1][e & 1] = (_Float16)ks;
        eh[e >> 1][e & 1] = (_Float16)((float)eh[e >> 1][e & 1] + E4c * ks);
        float k1 = (float)k1h[e >> 1][e & 1], k2 = (float)k2h[e >> 1][e & 1];
        float k3 = (float)k3h[e >> 1][e & 1];
        nys = yv + h * ((19372.0f / 6561.0f) * k1 + (-25360.0f / 2187.0f) * k2 +
                        (64448.0f / 6561.0f) * k3 + (-212.0f / 729.0f) * ks);
      } else if constexpr (S == 5) {
        k5h[e >> 1][e & 1] = (_Float16)ks;
        eh[e >> 1][e & 1] = (_Float16)((float)eh[e >> 1][e & 1] + E5c * ks);
        float k1 = (float)k1h[e >> 1][e & 1], k2 = (float)k2h[e >> 1][e & 1];
        float k3 = (float)k3h[e >> 1][e & 1], k4 = (float)k4h[e >> 1][e & 1];
        nys = yv + h * ((9017.0f / 3168.0f) * k1 + (-355.0f / 33.0f) * k2 +
                        (46732.0f / 5247.0f) * k3 + (49.0f / 176.0f) * k4 +
                        (-5103.0f / 18656.0f) * ks);
      } else if constexpr (S == 6) {
        eh[e >> 1][e & 1] = (_Float16)((float)eh[e >> 1][e & 1] + E6c * ks);
        float k1 = (float)k1h[e >> 1][e & 1];
        float k3 = (float)k3h[e >> 1][e & 1], k4 = (float)k4h[e >> 1][e & 1];
        float k5 = (float)k5h[e >> 1][e & 1];
        nys = yv + h * ((35.0f / 384.0f) * k1 + (500.0f / 1113.0f) * k3 +
                        (125.0f / 192.0f) * k4 + (-2187.0f / 6784.0f) * k5 +
                        (11.0f / 84.0f) * ks);
      } else {  // S == 7: k7 -> k2h slot (dead after S5); error norm
        k2h[e >> 1][e & 1] = (_Float16)ks;
        float ev = h * ((float)eh[e >> 1][e & 1] + E7c * ks);
        float sc = 1e-6f + 1e-3f * fmaxf(fabsf(yv), fabsf(ys[e]));
        float r = ev / sc;
        *errAcc += r * r;
        nys = 0.0f;
      }
      if constexpr (S <= 6) {
        ys[e] = nys;
        float av = ftanh(nys + bias4[ci]);
        int row = ((l >> 4) & 1) * 4 + q;
        int col = wv * 128 + ((l >> 5) * 4 + ci) * 16 + (l & 15);
        *(_Float16*)(actOut + row * 2048 + (((col >> 3) ^ row) << 4) + (col & 7) * 2) =
            (_Float16)av;
      }
    }
  }
}

__global__ __launch_bounds__(NTHR, 2) void k_step(
    int li, Ctl* __restrict__ c, u64* __restrict__ pk,
    const _Float16* __restrict__ Wf, float* __restrict__ yg,
    const half2v* __restrict__ dws, half2v* __restrict__ k1ws,
    const float* __restrict__ tau, const float* __restrict__ bias) {
  float t, dtv;
  if (li == 0) { t = 0.0f; dtv = 0.1f; }
  else { t = c->t; dtv = c->dt; }
  if (t >= 1.0f - 1e-7f) return;
  const float h = fminf(dtv, 1.0f - t);

  __shared__ _Float16 actL[2][8][1024];   // 32 KB ping-pong act
  __shared__ float sm[256];
  __shared__ float wsum[8];
  __shared__ float bc;

  const int tid = (int)threadIdx.x, bid = (int)blockIdx.x;
  const int l = tid & 63, wv = tid >> 6;
  const int lr16 = l & 15;
  const int rbase = bid * 8;
  char* A0 = (char*)&actL[0][0][0];
  char* A1 = (char*)&actL[1][0][0];
  const _Float16* wfb = Wf + (((size_t)wv << 8) << 9) + (l << 3);  // ct16 base wv*8

  // --- load state ---
  float y[16], ysr[16];
  half2v dh[8], k1h[8], k2h[8], k3h[8], k4h[8], k5h[8], eh[8];
  float itau4[4], bias4[4];
#pragma unroll
  for (int ci = 0; ci < 4; ++ci) {
    int col = wv * 128 + ((l >> 5) * 4 + ci) * 16 + lr16;
    itau4[ci] = 1.0f / tau[col];
    bias4[ci] = bias[col];
  }
#pragma unroll
  for (int ci = 0; ci < 4; ++ci)
#pragma unroll
    for (int q = 0; q < 4; ++q) {
      const int e = ci * 4 + q;
      int row = ((l >> 4) & 1) * 4 + q;
      int col = wv * 128 + ((l >> 5) * 4 + ci) * 16 + lr16;
      size_t off = (size_t)(rbase + row) * 1024 + col;
      float yv = yg[off];
      y[e] = yv;
      ysr[e] = yv;
      if (e & 1) {  // load pairs once (e even loads both halves? keep simple: scalar)
      }
      dh[e >> 1][e & 1] = dws[off >> 1][(int)(off & 1)];
    }

  f32x4 acc[8];
  if (li == 0) {
    // initial k1 = itau*(drive + W@tanh(y+b) - y): build act1 -> A1, GEMM
#pragma unroll
    for (int ci = 0; ci < 4; ++ci)
#pragma unroll
      for (int q = 0; q < 4; ++q) {
        const int e = ci * 4 + q;
        int row = ((l >> 4) & 1) * 4 + q;
        int col = wv * 128 + ((l >> 5) * 4 + ci) * 16 + lr16;
        float av = ftanh(y[e] + bias4[ci]);
        *(_Float16*)(A1 + row * 2048 + (((col >> 3) ^ row) << 4) + (col & 7) * 2) =
            (_Float16)av;
      }
    __syncthreads();
    gemm8(A1, wfb, l, acc);
    f32x4 sa[4];
    if (l >= 32) { sa[0] = acc[4]; sa[1] = acc[5]; sa[2] = acc[6]; sa[3] = acc[7]; }
    else         { sa[0] = acc[0]; sa[1] = acc[1]; sa[2] = acc[2]; sa[3] = acc[3]; }
#pragma unroll
    for (int ci = 0; ci < 4; ++ci)
#pragma unroll
      for (int q = 0; q < 4; ++q) {
        const int e = ci * 4 + q;
        k1h[e >> 1][e & 1] =
            (_Float16)(itau4[ci] * ((float)dh[e >> 1][e & 1] + sa[ci][q] - y[e]));
      }
    __syncthreads();
  } else {
#pragma unroll
    for (int ci = 0; ci < 4; ++ci)
#pragma unroll
      for (int q = 0; q < 4; ++q) {
        const int e = ci * 4 + q;
        int row = ((l >> 4) & 1) * 4 + q;
        int col = wv * 128 + ((l >> 5) * 4 + ci) * 16 + lr16;
        size_t off = (size_t)(rbase + row) * 1024 + col;
        k1h[e >> 1][e & 1] = k1ws[off >> 1][(int)(off & 1)];
      }
  }

  // --- the 7 stages (act ping-pong in LDS; no inter-block sync) ---
  stage_epi<1>(acc, h, y, ysr, dh, k1h, k2h, k3h, k4h, k5h, eh, itau4, bias4,
               A0, wv, l, nullptr);
  __syncthreads();
  gemm8(A0, wfb, l, acc);
  stage_epi<2>(acc, h, y, ysr, dh, k1h, k2h, k3h, k4h, k5h, eh, itau4, bias4,
               A1, wv, l, nullptr);
  __syncthreads();
  gemm8(A1, wfb, l, acc);
  stage_epi<3>(acc, h, y, ysr, dh, k1h, k2h, k3h, k4h, k5h, eh, itau4, bias4,
               A0, wv, l, nullptr);
  __syncthreads();
  gemm8(A0, wfb, l, acc);
  stage_epi<4>(acc, h, y, ysr, dh, k1h, k2h, k3h, k4h, k5h, eh, itau4, bias4,
               A1, wv, l, nullptr);
  __syncthreads();
  gemm8(A1, wfb, l, acc);
  stage_epi<5>(acc, h, y, ysr, dh, k1h, k2h, k3h, k4h, k5h, eh, itau4, bias4,
               A0, wv, l, nullptr);
  __syncthreads();
  gemm8(A0, wfb, l, acc);
  stage_epi<6>(acc, h, y, ysr, dh, k1h, k2h, k3h, k4h, k5h, eh, itau4, bias4,
               A1, wv, l, nullptr);   // act7 -> A1
  __syncthreads();
  gemm8(A1, wfb, l, acc);
  float errAcc = 0.0f;
  stage_epi<7>(acc, h, y, ysr, dh, k1h, k2h, k3h, k4h, k5h, eh, itau4, bias4,
               nullptr, wv, l, &errAcc);

  // --- block partial + single packed-flag grid exchange (r9-verified) ---
#pragma unroll
  for (int o = 32; o > 0; o >>= 1) errAcc += __shfl_down(errAcc, o, 64);
  if (l == 0) wsum[wv] = errAcc;
  __syncthreads();
  float sblk = 0.0f;
  if (tid == 0) {
#pragma unroll
    for (int w = 0; w < 8; ++w) sblk += wsum[w];
  }
  const u64 ep = (u64)(li + 2);
  const int slot = li & 1;
  if (tid == 0)
    AST64(&pk[bid * 8 + slot], (ep << 32) | (u64)__float_as_uint(sblk));
  if (tid < 256) {
    u64 v;
    do { v = ALD64(&pk[tid * 8 + slot]); } while ((v >> 32) < ep);
    sm[tid] = __uint_as_float((unsigned)v);
  }
  __syncthreads();
  if (tid < 64) {
    float a = sm[tid] + sm[tid + 64] + sm[tid + 128] + sm[tid + 192];
#pragma unroll
    for (int o = 1; o < 64; o <<= 1) a += __shfl_xor(a, o, 64);
    if (tid == 0) bc = a;
  }
  __syncthreads();
  float sd = bc;

  // --- controller (uniform across blocks) + commit + persist ---
  float enorm = fmaxf(sqrtf(sd / 2097152.0f), 1e-10f);
  bool acc_ok = (enorm <= 1.0f);
  if (acc_ok) {
#pragma unroll
    for (int e = 0; e < 16; ++e) y[e] = ysr[e];
#pragma unroll
    for (int i = 0; i < 8; ++i) k1h[i] = k2h[i];   // FSAL: k1 = k7
  }
#pragma unroll
  for (int ci = 0; ci < 4; ++ci)
#pragma unroll
    for (int q = 0; q < 4; ++q) {
      const int e = ci * 4 + q;
      int row = ((l >> 4) & 1) * 4 + q;
      int col = wv * 128 + ((l >> 5) * 4 + ci) * 16 + lr16;
      size_t off = (size_t)(rbase + row) * 1024 + col;
      yg[off] = y[e];
      k1ws[off >> 1][(int)(off & 1)] = k1h[e >> 1][e & 1];
    }
  if (bid == 0 && tid == 0) {
    float factor = fminf(fmaxf(0.9f * powf(enorm, -0.2f), 0.2f), 5.0f);
    c->dt = dtv * factor;
    c->t = acc_ok ? (t + h) : t;
  }
}

extern "C" void kernel_launch(void* const* d_in, const int* in_sizes, int n_in,
                              void* d_out, int out_size, void* d_ws, size_t ws_size,
                              hipStream_t stream) {
  const float* inp = (const float*)d_in[0];
  const f4* prev = (const f4*)d_in[1];
  const float* tau = (const float*)d_in[2];
  const float* W = (const float*)d_in[3];
  const float* iw = (const float*)d_in[4];
  const float* bias = (const float*)d_in[5];
  float* yg = (float*)d_out;

  char* ws = (char*)d_ws;
  const size_t MB = 1024 * 1024;
  u64* pk = (u64*)ws;                              // 16 KB
  Ctl* c = (Ctl*)(ws + 16384);
  _Float16* Wf = (_Float16*)(ws + 64 * 1024);      // 2 MB
  half2v* dws = (half2v*)(ws + 64 * 1024 + 2 * MB);   // 4 MB
  half2v* k1ws = (half2v*)(ws + 64 * 1024 + 6 * MB);  // 4 MB

  k_zero<<<4, 512, 0, stream>>>(pk);
  k_prep<<<512, 256, 0, stream>>>(W, Wf);
  k_init<<<2048, 256, 0, stream>>>(prev, (const f4*)inp, (const f4*)iw,
                                   (f4*)yg, (half4v*)dws);
  for (int s = 0; s < 40; ++s) {
    k_step<<<NBLK, NTHR, 0, stream>>>(s, c, pk, Wf, yg, dws, k1ws, tau, bias);
  }
}

// Round 12
// 885.648 us; speedup vs baseline: 2.4016x; 1.2798x over previous
//
#include <hip/hip_runtime.h>
#include <math.h>

// CTRNN + adaptive DOPRI5 (B=2048, N=1024). Round 12 = Round 11 (launch per
// step; block = 8 complete rows; act in block LDS; single packed-flag
// exchange per step; FSAL) + two GEMM fixes:
//  1. per-CU K-phase rotation rot=(bid>>3)&31 -> the 32 CUs of an XCD
//     stream Wf at different phases (kills L2 channel hotspot from
//     lockstep same-address reads by all blocks).
//  2. 2-deep named-register B prefetch (bA/bB) + no min-wave bound
//     (VGPR ~220) -> counted vmcnt pipelining instead of drain-to-0.

typedef float f4 __attribute__((ext_vector_type(4)));
typedef float f32x4 __attribute__((ext_vector_type(4)));
typedef _Float16 half8v __attribute__((ext_vector_type(8)));
typedef _Float16 half4v __attribute__((ext_vector_type(4)));
typedef _Float16 half2v __attribute__((ext_vector_type(2)));
typedef unsigned long long u64;

#define NBLK 256
#define NTHR 512

#define E1c (71.0f / 57600.0f)
#define E3c (-71.0f / 16695.0f)
#define E4c (71.0f / 1920.0f)
#define E5c (-17253.0f / 339200.0f)
#define E6c (22.0f / 525.0f)
#define E7c (-1.0f / 40.0f)

#define ALD64(p) __hip_atomic_load((p), __ATOMIC_ACQUIRE, __HIP_MEMORY_SCOPE_AGENT)
#define AST64(p, v) __hip_atomic_store((p), (v), __ATOMIC_RELEASE, __HIP_MEMORY_SCOPE_AGENT)

struct Ctl { float t, dt; };

__global__ void k_zero(u64* pk) {
  int i = blockIdx.x * blockDim.x + threadIdx.x;
  if (i < 2048) pk[i] = 0ull;
}

__device__ __forceinline__ float ftanh(float x) {
  x = fminf(fmaxf(x, -9.0f), 9.0f);
  float e = __expf(2.0f * x);
  return (e - 1.0f) / (e + 1.0f);
}

// Wf[((ct16*32 + kb)*64 + l)*8 + j] = W[ct16*16 + (l&15)][kb*32 + (l>>4)*8 + j]
__global__ void k_prep(const float* __restrict__ W, _Float16* __restrict__ Wf) {
  int i = blockIdx.x * blockDim.x + threadIdx.x;   // 0..131071
  int l = i & 63, kb = (i >> 6) & 31, ct = i >> 11;
  const float* src = W + (size_t)(ct * 16 + (l & 15)) * 1024 + kb * 32 + (l >> 4) * 8;
  half8v o;
#pragma unroll
  for (int j = 0; j < 8; ++j) o[j] = (_Float16)src[j];
  *(half8v*)(Wf + ((size_t)i << 3)) = o;
}

// y := prev (in d_out); drive := inp*iw (fp16)
__global__ void k_init(const f4* __restrict__ prev, const f4* __restrict__ inp,
                       const f4* __restrict__ iw, f4* __restrict__ y,
                       half4v* __restrict__ dws) {
  int i = blockIdx.x * blockDim.x + threadIdx.x;   // f4 units
  f4 p = prev[i];
  y[i] = p;
  f4 v = inp[i];
  f4 w = iw[i & 255];
  half4v d;
#pragma unroll
  for (int j = 0; j < 4; ++j) d[j] = (_Float16)(v[j] * w[j]);
  dws[i] = d;
}

// acc[8] = rec fragments for this wave's 8 col-tiles. A from LDS act
// (row = l&7, XOR-swizzled granules); B from fragment-contiguous Wf with
// per-CU K-phase rotation + 2-deep register double-buffer.
__device__ __forceinline__ void gemm8(const char* actB,
                                      const _Float16* __restrict__ wfb,
                                      int l, int rot, f32x4 acc[8]) {
#pragma unroll
  for (int ct = 0; ct < 8; ++ct)
#pragma unroll
    for (int q = 0; q < 4; ++q) acc[ct][q] = 0.0f;
  const int r = l & 7, lk = l >> 4;
  const char* arow = actB + r * 2048;
  half8v bA[8], bB[8];
#pragma unroll
  for (int ct = 0; ct < 8; ++ct)
    bA[ct] = *(const half8v*)(wfb + (((ct << 5) + rot) << 9));
#pragma unroll 1
  for (int it = 0; it < 32; it += 2) {
    const int kb0 = (it + rot) & 31;
    const int kb1 = (it + 1 + rot) & 31;
    const int kb2 = (it + 2 + rot) & 31;
    half8v a0 = *(const half8v*)(arow + ((((kb0 << 2) | lk) ^ r) << 4));
#pragma unroll
    for (int ct = 0; ct < 8; ++ct)
      bB[ct] = *(const half8v*)(wfb + (((ct << 5) + kb1) << 9));
#pragma unroll
    for (int ct = 0; ct < 8; ++ct)
      acc[ct] = __builtin_amdgcn_mfma_f32_16x16x32_f16(a0, bA[ct], acc[ct], 0, 0, 0);
    half8v a1 = *(const half8v*)(arow + ((((kb1 << 2) | lk) ^ r) << 4));
#pragma unroll
    for (int ct = 0; ct < 8; ++ct)
      bA[ct] = *(const half8v*)(wfb + (((ct << 5) + kb2) << 9));
#pragma unroll
    for (int ct = 0; ct < 8; ++ct)
      acc[ct] = __builtin_amdgcn_mfma_f32_16x16x32_f16(a1, bB[ct], acc[ct], 0, 0, 0);
  }
}

// e = ci*4 + q. Thread owns rows ((l>>4)&1)*4+q, cols wv*128+((l>>5)*4+ci)*16+(l&15).
template <int S>
__device__ __forceinline__ void stage_epi(
    const f32x4 acc[8], float h,
    float* y, float* ys, const half2v* dh,
    half2v* k1h, half2v* k2h, half2v* k3h, half2v* k4h, half2v* k5h, half2v* eh,
    const float* itau4, const float* bias4,
    char* actOut, int wv, int l, float* errAcc) {
  f32x4 sa[4];
  if (l >= 32) { sa[0] = acc[4]; sa[1] = acc[5]; sa[2] = acc[6]; sa[3] = acc[7]; }
  else         { sa[0] = acc[0]; sa[1] = acc[1]; sa[2] = acc[2]; sa[3] = acc[3]; }
#pragma unroll
  for (int ci = 0; ci < 4; ++ci) {
#pragma unroll
    for (int q = 0; q < 4; ++q) {
      const int e = ci * 4 + q;
      float yv = y[e];
      float ks;
      if constexpr (S == 1) {
        ks = (float)k1h[e >> 1][e & 1];
      } else {
        ks = itau4[ci] * ((float)dh[e >> 1][e & 1] + sa[ci][q] - ys[e]);
      }
      float nys;
      if constexpr (S == 1) {
        eh[e >> 1][e & 1] = (_Float16)(E1c * ks);
        nys = yv + h * (0.2f * ks);
      } else if constexpr (S == 2) {
        k2h[e >> 1][e & 1] = (_Float16)ks;
        float k1 = (float)k1h[e >> 1][e & 1];
        nys = yv + h * ((3.0f / 40.0f) * k1 + (9.0f / 40.0f) * ks);
      } else if constexpr (S == 3) {
        k3h[e >> 1][e & 1] = (_Float16)ks;
        eh[e >> 1][e & 1] = (_Float16)((float)eh[e >> 1][e & 1] + E3c * ks);
        float k1 = (float)k1h[e >> 1][e & 1], k2 = (float)k2h[e >> 1][e & 1];
        nys = yv + h * ((44.0f / 45.0f) * k1 + (-56.0f / 15.0f) * k2 + (32.0f / 9.0f) * ks);
      } else if constexpr (S == 4) {
        k4h[e >> 1][e & 1] = (_Float16)ks;
        eh[e >> 1][e & 1] = (_Float16)((float)eh[e >> 1][e & 1] + E4c * ks);
        float k1 = (float)k1h[e >> 1][e & 1], k2 = (float)k2h[e >> 1][e & 1];
        float k3 = (float)k3h[e >> 1][e & 1];
        nys = yv + h * ((19372.0f / 6561.0f) * k1 + (-25360.0f / 2187.0f) * k2 +
                        (64448.0f / 6561.0f) * k3 + (-212.0f / 729.0f) * ks);
      } else if constexpr (S == 5) {
        k5h[e >> 1][e & 1] = (_Float16)ks;
        eh[e >> 1][e & 1] = (_Float16)((float)eh[e >> 1][e & 1] + E5c * ks);
        float k1 = (float)k1h[e >> 1][e & 1], k2 = (float)k2h[e >> 1][e & 1];
        float k3 = (float)k3h[e >> 1][e & 1], k4 = (float)k4h[e >> 1][e & 1];
        nys = yv + h * ((9017.0f / 3168.0f) * k1 + (-355.0f / 33.0f) * k2 +
                        (46732.0f / 5247.0f) * k3 + (49.0f / 176.0f) * k4 +
                        (-5103.0f / 18656.0f) * ks);
      } else if constexpr (S == 6) {
        eh[e >> 1][e & 1] = (_Float16)((float)eh[e >> 1][e & 1] + E6c * ks);
        float k1 = (float)k1h[e >> 1][e & 1];
        float k3 = (float)k3h[e >> 1][e & 1], k4 = (float)k4h[e >> 1][e & 1];
        float k5 = (float)k5h[e >> 1][e & 1];
        nys = yv + h * ((35.0f / 384.0f) * k1 + (500.0f / 1113.0f) * k3 +
                        (125.0f / 192.0f) * k4 + (-2187.0f / 6784.0f) * k5 +
                        (11.0f / 84.0f) * ks);
      } else {  // S == 7: k7 -> k2h slot (dead after S5); error norm
        k2h[e >> 1][e & 1] = (_Float16)ks;
        float ev = h * ((float)eh[e >> 1][e & 1] + E7c * ks);
        float sc = 1e-6f + 1e-3f * fmaxf(fabsf(yv), fabsf(ys[e]));
        float r = ev / sc;
        *errAcc += r * r;
        nys = 0.0f;
      }
      if constexpr (S <= 6) {
        ys[e] = nys;
        float av = ftanh(nys + bias4[ci]);
        int row = ((l >> 4) & 1) * 4 + q;
        int col = wv * 128 + ((l >> 5) * 4 + ci) * 16 + (l & 15);
        *(_Float16*)(actOut + row * 2048 + (((col >> 3) ^ row) << 4) + (col & 7) * 2) =
            (_Float16)av;
      }
    }
  }
}

__global__ __launch_bounds__(NTHR) void k_step(
    int li, Ctl* __restrict__ c, u64* __restrict__ pk,
    const _Float16* __restrict__ Wf, float* __restrict__ yg,
    const half2v* __restrict__ dws, half2v* __restrict__ k1ws,
    const float* __restrict__ tau, const float* __restrict__ bias) {
  float t, dtv;
  if (li == 0) { t = 0.0f; dtv = 0.1f; }
  else { t = c->t; dtv = c->dt; }
  if (t >= 1.0f - 1e-7f) return;
  const float h = fminf(dtv, 1.0f - t);

  __shared__ _Float16 actL[2][8][1024];   // 32 KB ping-pong act
  __shared__ float sm[256];
  __shared__ float wsum[8];
  __shared__ float bc;

  const int tid = (int)threadIdx.x, bid = (int)blockIdx.x;
  const int l = tid & 63, wv = tid >> 6;
  const int lr16 = l & 15;
  const int rbase = bid * 8;
  const int rot = (bid >> 3) & 31;     // per-CU K phase (32 CUs/XCD distinct)
  char* A0 = (char*)&actL[0][0][0];
  char* A1 = (char*)&actL[1][0][0];
  const _Float16* wfb = Wf + ((size_t)wv << 17) + (l << 3);

  // --- load state ---
  float y[16], ysr[16];
  half2v dh[8], k1h[8], k2h[8], k3h[8], k4h[8], k5h[8], eh[8];
  float itau4[4], bias4[4];
#pragma unroll
  for (int ci = 0; ci < 4; ++ci) {
    int col = wv * 128 + ((l >> 5) * 4 + ci) * 16 + lr16;
    itau4[ci] = 1.0f / tau[col];
    bias4[ci] = bias[col];
  }
#pragma unroll
  for (int ci = 0; ci < 4; ++ci)
#pragma unroll
    for (int q = 0; q < 4; ++q) {
      const int e = ci * 4 + q;
      int row = ((l >> 4) & 1) * 4 + q;
      int col = wv * 128 + ((l >> 5) * 4 + ci) * 16 + lr16;
      size_t off = (size_t)(rbase + row) * 1024 + col;
      float yv = yg[off];
      y[e] = yv;
      ysr[e] = yv;
      dh[e >> 1][e & 1] = dws[off >> 1][(int)(off & 1)];
    }

  f32x4 acc[8];
  if (li == 0) {
    // initial k1 = itau*(drive + W@tanh(y+b) - y)
#pragma unroll
    for (int ci = 0; ci < 4; ++ci)
#pragma unroll
      for (int q = 0; q < 4; ++q) {
        const int e = ci * 4 + q;
        int row = ((l >> 4) & 1) * 4 + q;
        int col = wv * 128 + ((l >> 5) * 4 + ci) * 16 + lr16;
        float av = ftanh(y[e] + bias4[ci]);
        *(_Float16*)(A1 + row * 2048 + (((col >> 3) ^ row) << 4) + (col & 7) * 2) =
            (_Float16)av;
      }
    __syncthreads();
    gemm8(A1, wfb, l, rot, acc);
    f32x4 sa[4];
    if (l >= 32) { sa[0] = acc[4]; sa[1] = acc[5]; sa[2] = acc[6]; sa[3] = acc[7]; }
    else         { sa[0] = acc[0]; sa[1] = acc[1]; sa[2] = acc[2]; sa[3] = acc[3]; }
#pragma unroll
    for (int ci = 0; ci < 4; ++ci)
#pragma unroll
      for (int q = 0; q < 4; ++q) {
        const int e = ci * 4 + q;
        k1h[e >> 1][e & 1] =
            (_Float16)(itau4[ci] * ((float)dh[e >> 1][e & 1] + sa[ci][q] - y[e]));
      }
    __syncthreads();
  } else {
#pragma unroll
    for (int ci = 0; ci < 4; ++ci)
#pragma unroll
      for (int q = 0; q < 4; ++q) {
        const int e = ci * 4 + q;
        int row = ((l >> 4) & 1) * 4 + q;
        int col = wv * 128 + ((l >> 5) * 4 + ci) * 16 + lr16;
        size_t off = (size_t)(rbase + row) * 1024 + col;
        k1h[e >> 1][e & 1] = k1ws[off >> 1][(int)(off & 1)];
      }
  }

  // --- the 7 stages (act ping-pong in LDS; no inter-block sync) ---
  stage_epi<1>(acc, h, y, ysr, dh, k1h, k2h, k3h, k4h, k5h, eh, itau4, bias4,
               A0, wv, l, nullptr);
  __syncthreads();
  gemm8(A0, wfb, l, rot, acc);
  stage_epi<2>(acc, h, y, ysr, dh, k1h, k2h, k3h, k4h, k5h, eh, itau4, bias4,
               A1, wv, l, nullptr);
  __syncthreads();
  gemm8(A1, wfb, l, rot, acc);
  stage_epi<3>(acc, h, y, ysr, dh, k1h, k2h, k3h, k4h, k5h, eh, itau4, bias4,
               A0, wv, l, nullptr);
  __syncthreads();
  gemm8(A0, wfb, l, rot, acc);
  stage_epi<4>(acc, h, y, ysr, dh, k1h, k2h, k3h, k4h, k5h, eh, itau4, bias4,
               A1, wv, l, nullptr);
  __syncthreads();
  gemm8(A1, wfb, l, rot, acc);
  stage_epi<5>(acc, h, y, ysr, dh, k1h, k2h, k3h, k4h, k5h, eh, itau4, bias4,
               A0, wv, l, nullptr);
  __syncthreads();
  gemm8(A0, wfb, l, rot, acc);
  stage_epi<6>(acc, h, y, ysr, dh, k1h, k2h, k3h, k4h, k5h, eh, itau4, bias4,
               A1, wv, l, nullptr);   // act7 -> A1
  __syncthreads();
  gemm8(A1, wfb, l, rot, acc);
  float errAcc = 0.0f;
  stage_epi<7>(acc, h, y, ysr, dh, k1h, k2h, k3h, k4h, k5h, eh, itau4, bias4,
               nullptr, wv, l, &errAcc);

  // --- block partial + single packed-flag grid exchange (r9/r11-verified) ---
#pragma unroll
  for (int o = 32; o > 0; o >>= 1) errAcc += __shfl_down(errAcc, o, 64);
  if (l == 0) wsum[wv] = errAcc;
  __syncthreads();
  float sblk = 0.0f;
  if (tid == 0) {
#pragma unroll
    for (int w = 0; w < 8; ++w) sblk += wsum[w];
  }
  const u64 ep = (u64)(li + 2);
  const int slot = li & 1;
  if (tid == 0)
    AST64(&pk[bid * 8 + slot], (ep << 32) | (u64)__float_as_uint(sblk));
  if (tid < 256) {
    u64 v;
    do { v = ALD64(&pk[tid * 8 + slot]); } while ((v >> 32) < ep);
    sm[tid] = __uint_as_float((unsigned)v);
  }
  __syncthreads();
  if (tid < 64) {
    float a = sm[tid] + sm[tid + 64] + sm[tid + 128] + sm[tid + 192];
#pragma unroll
    for (int o = 1; o < 64; o <<= 1) a += __shfl_xor(a, o, 64);
    if (tid == 0) bc = a;
  }
  __syncthreads();
  float sd = bc;

  // --- controller (uniform) + commit + persist ---
  float enorm = fmaxf(sqrtf(sd / 2097152.0f), 1e-10f);
  bool acc_ok = (enorm <= 1.0f);
  if (acc_ok) {
#pragma unroll
    for (int e = 0; e < 16; ++e) y[e] = ysr[e];
#pragma unroll
    for (int i = 0; i < 8; ++i) k1h[i] = k2h[i];   // FSAL: k1 = k7
  }
#pragma unroll
  for (int ci = 0; ci < 4; ++ci)
#pragma unroll
    for (int q = 0; q < 4; ++q) {
      const int e = ci * 4 + q;
      int row = ((l >> 4) & 1) * 4 + q;
      int col = wv * 128 + ((l >> 5) * 4 + ci) * 16 + lr16;
      size_t off = (size_t)(rbase + row) * 1024 + col;
      yg[off] = y[e];
      k1ws[off >> 1][(int)(off & 1)] = k1h[e >> 1][e & 1];
    }
  if (bid == 0 && tid == 0) {
    float factor = fminf(fmaxf(0.9f * powf(enorm, -0.2f), 0.2f), 5.0f);
    c->dt = dtv * factor;
    c->t = acc_ok ? (t + h) : t;
  }
}

extern "C" void kernel_launch(void* const* d_in, const int* in_sizes, int n_in,
                              void* d_out, int out_size, void* d_ws, size_t ws_size,
                              hipStream_t stream) {
  const float* inp = (const float*)d_in[0];
  const f4* prev = (const f4*)d_in[1];
  const float* tau = (const float*)d_in[2];
  const float* W = (const float*)d_in[3];
  const float* iw = (const float*)d_in[4];
  const float* bias = (const float*)d_in[5];
  float* yg = (float*)d_out;

  char* ws = (char*)d_ws;
  const size_t MB = 1024 * 1024;
  u64* pk = (u64*)ws;                              // 16 KB
  Ctl* c = (Ctl*)(ws + 16384);
  _Float16* Wf = (_Float16*)(ws + 64 * 1024);      // 2 MB
  half2v* dws = (half2v*)(ws + 64 * 1024 + 2 * MB);   // 4 MB
  half2v* k1ws = (half2v*)(ws + 64 * 1024 + 6 * MB);  // 4 MB

  k_zero<<<4, 512, 0, stream>>>(pk);
  k_prep<<<512, 256, 0, stream>>>(W, Wf);
  k_init<<<2048, 256, 0, stream>>>(prev, (const f4*)inp, (const f4*)iw,
                                   (f4*)yg, (half4v*)dws);
  for (int s = 0; s < 40; ++s) {
    k_step<<<NBLK, NTHR, 0, stream>>>(s, c, pk, Wf, yg, dws, k1ws, tau, bias);
  }
}